// Round 4
// baseline (3741.703 us; speedup 1.0000x reference)
//
#include <hip/hip_runtime.h>

#define N_E 8192
#define E_DIM 512
#define NROWS 32768          // 16*2048
#define TOT_ELEMS 16777216   // 16*2048*512
#define BETA 0.25f
#define NTHREADS 512

#define BM 128
#define BN 256
#define BK 32

// ---------------- Kernel 1: accurate row norms ||z_r||^2 (fp64 acc -> fp32) ------------
// Correctly-rounded z2 lands in the same binade as np's pairwise-fp32 z2 (w.h.p.),
// which is all the quantized-comparison replication needs (shift by exact k*ulp).
__global__ __launch_bounds__(256) void z2_kernel(const float* __restrict__ z,
                                                 float* __restrict__ z2) {
    int row  = blockIdx.x * 4 + (threadIdx.x >> 6);
    int lane = threadIdx.x & 63;
    const float4* p = (const float4*)(z + (size_t)row * E_DIM);
    double s = 0.0;
#pragma unroll
    for (int it = 0; it < 2; ++it) {
        float4 v = p[lane + it * 64];
        s += (double)v.x * v.x + (double)v.y * v.y
           + (double)v.z * v.z + (double)v.w * v.w;
    }
#pragma unroll
    for (int off = 32; off > 0; off >>= 1) s += __shfl_down(s, off);
    if (lane == 0) z2[row] = (float)s;
}

// ---------------- Kernel 2: fused matmul + REFERENCE-SEMANTICS argmin -----------------
// Replicates np fp32: w(r,n) = fl32( z2_r - 2*M_rn )  [e2 provably absorbed: e2 < ulp/2]
// argmin over quantized w, ties -> LOWEST index (np.argmin first-occurrence).
__global__ __launch_bounds__(NTHREADS) void argmin_kernel(const float* __restrict__ z,
                                                          const float* __restrict__ emb,
                                                          const float* __restrict__ z2s,
                                                          float* __restrict__ idxf_out) {
    __shared__ __align__(16) float smem[12288];   // 48 KB: As[32][128] @0, Bs[32][256] @4096
    float* As = smem;
    float* Bs = smem + 4096;

    const int tid = threadIdx.x;
    const int tx = tid & 31;          // 32 col-groups of 8  -> 256 cols
    const int ty = tid >> 5;          // 16 row-groups of 8  -> 128 rows
    const int row0 = blockIdx.x * BM;

    const int smA = tid & 127, kqA = tid >> 7;   // A: 128 rows, 4 k-chunks
    const int smB = tid & 255, kqB = tid >> 8;   // B: 256 rows, 2 k-chunks

    float z2r[8];
#pragma unroll
    for (int i = 0; i < 8; ++i) z2r[i] = z2s[row0 + ty * 8 + i];

    float minw[8];
    int   mini[8];
#pragma unroll
    for (int i = 0; i < 8; ++i) { minw[i] = 3.4e38f; mini[i] = 0; }

    float acc[8][8];

    for (int n0 = 0; n0 < N_E; n0 += BN) {
#pragma unroll
        for (int i = 0; i < 8; ++i)
#pragma unroll
            for (int j = 0; j < 8; ++j) acc[i][j] = 0.f;

        for (int k0 = 0; k0 < E_DIM; k0 += BK) {
            // stage A (z) k-major
#pragma unroll
            for (int it = 0; it < 2; ++it) {
                int kk = kqA * 8 + it * 4;
                float4 av = *(const float4*)(z + (size_t)(row0 + smA) * E_DIM + k0 + kk);
                As[(kk + 0) * 128 + smA] = av.x; As[(kk + 1) * 128 + smA] = av.y;
                As[(kk + 2) * 128 + smA] = av.z; As[(kk + 3) * 128 + smA] = av.w;
            }
            // stage B (emb) k-major
#pragma unroll
            for (int it = 0; it < 4; ++it) {
                int kk = kqB * 16 + it * 4;
                float4 bv = *(const float4*)(emb + (size_t)(n0 + smB) * E_DIM + k0 + kk);
                Bs[(kk + 0) * 256 + smB] = bv.x; Bs[(kk + 1) * 256 + smB] = bv.y;
                Bs[(kk + 2) * 256 + smB] = bv.z; Bs[(kk + 3) * 256 + smB] = bv.w;
            }
            __syncthreads();
#pragma unroll 8
            for (int k = 0; k < BK; ++k) {
                float4 a0 = *(const float4*)&As[k * 128 + ty * 8];
                float4 a1 = *(const float4*)&As[k * 128 + ty * 8 + 4];
                float4 b0 = *(const float4*)&Bs[k * 256 + tx * 8];
                float4 b1 = *(const float4*)&Bs[k * 256 + tx * 8 + 4];
                float av[8] = {a0.x, a0.y, a0.z, a0.w, a1.x, a1.y, a1.z, a1.w};
                float bv[8] = {b0.x, b0.y, b0.z, b0.w, b1.x, b1.y, b1.z, b1.w};
#pragma unroll
                for (int i = 0; i < 8; ++i)
#pragma unroll
                    for (int j = 0; j < 8; ++j) acc[i][j] += av[i] * bv[j];
            }
            __syncthreads();
        }
        // fold: w = fl(z2 - 2*acc)  (2*acc exact => one rounding; FMA-contraction safe)
        // n ascending within thread; strict < keeps the earliest (lowest) index.
#pragma unroll
        for (int j = 0; j < 8; ++j) {
            int n = n0 + tx * 8 + j;
#pragma unroll
            for (int i = 0; i < 8; ++i) {
                float w = z2r[i] - 2.f * acc[i][j];
                if (w < minw[i]) { minw[i] = w; mini[i] = n; }
            }
        }
    }

    // cross-thread reduction (32 tx-threads per row), ties -> lowest index
    __syncthreads();
    float* rvals = As;                 // 4096 floats
    int*   ridx  = (int*)Bs;           // 4096 ints
#pragma unroll
    for (int i = 0; i < 8; ++i) {
        int r = ty * 8 + i;
        rvals[r * 32 + tx] = minw[i];
        ridx [r * 32 + tx] = mini[i];
    }
    __syncthreads();
    if (tid < BM) {
        float bv = rvals[tid * 32];
        int   bi = ridx [tid * 32];
#pragma unroll
        for (int t = 1; t < 32; ++t) {
            float v  = rvals[tid * 32 + t];
            int   ii = ridx [tid * 32 + t];
            if (v < bv || (v == bv && ii < bi)) { bv = v; bi = ii; }
        }
        idxf_out[row0 + tid] = (float)bi;
    }
}

// ---------------- Kernel 3: gather + straight-through output + loss ----------------
__global__ __launch_bounds__(256) void output_kernel(const float* __restrict__ z,
                                                     const float* __restrict__ mask,
                                                     const float* __restrict__ emb,
                                                     const float* __restrict__ idxf,
                                                     float* __restrict__ out0,
                                                     float* __restrict__ loss) {
    const int nth = gridDim.x * blockDim.x;
    int t = blockIdx.x * blockDim.x + threadIdx.x;
    const float4* z4 = (const float4*)z;
    const float4* e4 = (const float4*)emb;
    float4* o4 = (float4*)out0;
    float partial = 0.f;
    for (int f = t; f < TOT_ELEMS / 4; f += nth) {
        int row = f >> 7;            // 128 float4 per 512-elem row
        int col = f & 127;
        int id  = (int)idxf[row];
        float m = mask[row];
        float4 zv = z4[f];
        float4 qv = e4[id * 128 + col];
        float dx = qv.x - zv.x, dy = qv.y - zv.y;
        float dz = qv.z - zv.z, dw = qv.w - zv.w;
        float4 ov;                   // z + (z_q - z): fp32 replication of ST estimator
        ov.x = zv.x + dx; ov.y = zv.y + dy;
        ov.z = zv.z + dz; ov.w = zv.w + dw;
        o4[f] = ov;
        partial += (dx * dx + dy * dy + dz * dz + dw * dw) * m;
    }
#pragma unroll
    for (int off = 32; off > 0; off >>= 1) partial += __shfl_down(partial, off);
    __shared__ float wsum[4];
    int lane = threadIdx.x & 63, w = threadIdx.x >> 6;
    if (lane == 0) wsum[w] = partial;
    __syncthreads();
    if (threadIdx.x == 0) {
        float s = wsum[0] + wsum[1] + wsum[2] + wsum[3];
        atomicAdd(loss, s * ((1.f + BETA) / (float)TOT_ELEMS));
    }
}

// ---------------- launcher (no d_ws usage) ----------------
extern "C" void kernel_launch(void* const* d_in, const int* in_sizes, int n_in,
                              void* d_out, int out_size, void* d_ws, size_t ws_size,
                              hipStream_t stream) {
    const float* z    = (const float*)d_in[0];   // (16,2048,512)
    const float* mask = (const float*)d_in[1];   // (16,2048)
    const float* emb  = (const float*)d_in[2];   // (8192,512)

    float* out0 = (float*)d_out;                 // z_q_st: 16777216 floats
    float* out1 = out0 + TOT_ELEMS;              // idx as float: 32768
    float* loss = out1 + NROWS;                  // scalar

    float* z2stash = out0;                       // out0[0:32768]; overwritten by output_kernel

    hipMemsetAsync(loss, 0, sizeof(float), stream);
    z2_kernel<<<NROWS / 4, 256, 0, stream>>>(z, z2stash);
    argmin_kernel<<<NROWS / BM, NTHREADS, 0, stream>>>(z, emb, z2stash, out1);
    output_kernel<<<4096, 256, 0, stream>>>(z, mask, emb, out1, out0, loss);
}

// Round 5
// 3250.016 us; speedup vs baseline: 1.1513x; 1.1513x over previous
//
#include <hip/hip_runtime.h>

#define N_E 8192
#define E_DIM 512
#define NROWS 32768          // 16*2048
#define TOT_ELEMS 16777216   // 16*2048*512
#define BETA 0.25f
#define NTHREADS 512

#define BM 128
#define BN 256
#define BK 32
#define NTILES 512           // (N_E/BN) * (E_DIM/BK) = 32 * 16

// ---------------- Kernel 1: accurate row norms ||z_r||^2 (fp64 acc -> fp32) ------------
__global__ __launch_bounds__(256) void z2_kernel(const float* __restrict__ z,
                                                 float* __restrict__ z2) {
    int row  = blockIdx.x * 4 + (threadIdx.x >> 6);
    int lane = threadIdx.x & 63;
    const float4* p = (const float4*)(z + (size_t)row * E_DIM);
    double s = 0.0;
#pragma unroll
    for (int it = 0; it < 2; ++it) {
        float4 v = p[lane + it * 64];
        s += (double)v.x * v.x + (double)v.y * v.y
           + (double)v.z * v.z + (double)v.w * v.w;
    }
#pragma unroll
    for (int off = 32; off > 0; off >>= 1) s += __shfl_down(s, off);
    if (lane == 0) z2[row] = (float)s;
}

// ---------------- Kernel 2: fused matmul + reference-semantics argmin -----------------
// w(r,n) = fl32(z2_r - 2*M_rn), argmin with ties -> lowest index. M accumulated as the
// SAME sequential-k fp32 FMA chain as the passing R4 kernel (bit-identical results).
// Microtile 16 rows x 4 cols: A-reads are wave-uniform broadcasts, B-read is a single
// conflict-free ds_read_b128 (lane stride 16B). Register prefetch pipelines global->LDS.
__global__ __launch_bounds__(NTHREADS, 2) void argmin_kernel(const float* __restrict__ z,
                                                             const float* __restrict__ emb,
                                                             const float* __restrict__ z2s,
                                                             float* __restrict__ idxf_out) {
    __shared__ __align__(16) float As[BK * BM];   // 16 KB, k-major
    __shared__ __align__(16) float Bs[BK * BN];   // 32 KB, k-major

    const int tid = threadIdx.x;
    const int tx = tid & 63;          // 64 col-groups of 4 -> 256 cols (wave-varying)
    const int ty = tid >> 6;          // 8 row-groups of 16 -> 128 rows (wave-uniform)
    const int row0 = blockIdx.x * BM;

    const int smA = tid & 127, kqA = (tid >> 7) << 3;   // A: 128 rows x 4 chunks of 8 k
    const int smB = tid & 255, kqB = (tid >> 8) << 4;   // B: 256 rows x 2 chunks of 16 k

    float z2r[16];
#pragma unroll
    for (int i = 0; i < 16; ++i) z2r[i] = z2s[row0 + ty * 16 + i];

    float minw[16];
    int   mini[16];
#pragma unroll
    for (int i = 0; i < 16; ++i) { minw[i] = 3.4e38f; mini[i] = 0; }

    float acc[16][4];
#pragma unroll
    for (int i = 0; i < 16; ++i)
#pragma unroll
        for (int j = 0; j < 4; ++j) acc[i][j] = 0.f;

    const float* zA = z   + (size_t)(row0 + smA) * E_DIM + kqA;
    const float* eB = emb + (size_t)smB * E_DIM + kqB;

    // prefetch tile g=0 (n0=0, k0=0)
    float4 pa0 = *(const float4*)(zA + 0);
    float4 pa1 = *(const float4*)(zA + 4);
    float4 pb0 = *(const float4*)(eB + 0);
    float4 pb1 = *(const float4*)(eB + 4);
    float4 pb2 = *(const float4*)(eB + 8);
    float4 pb3 = *(const float4*)(eB + 12);

    for (int g = 0; g < NTILES; ++g) {
        // ---- write tile g (in regs) to LDS; consecutive lanes -> consecutive banks (free)
        As[(kqA + 0) * BM + smA] = pa0.x; As[(kqA + 1) * BM + smA] = pa0.y;
        As[(kqA + 2) * BM + smA] = pa0.z; As[(kqA + 3) * BM + smA] = pa0.w;
        As[(kqA + 4) * BM + smA] = pa1.x; As[(kqA + 5) * BM + smA] = pa1.y;
        As[(kqA + 6) * BM + smA] = pa1.z; As[(kqA + 7) * BM + smA] = pa1.w;
        Bs[(kqB +  0) * BN + smB] = pb0.x; Bs[(kqB +  1) * BN + smB] = pb0.y;
        Bs[(kqB +  2) * BN + smB] = pb0.z; Bs[(kqB +  3) * BN + smB] = pb0.w;
        Bs[(kqB +  4) * BN + smB] = pb1.x; Bs[(kqB +  5) * BN + smB] = pb1.y;
        Bs[(kqB +  6) * BN + smB] = pb1.z; Bs[(kqB +  7) * BN + smB] = pb1.w;
        Bs[(kqB +  8) * BN + smB] = pb2.x; Bs[(kqB +  9) * BN + smB] = pb2.y;
        Bs[(kqB + 10) * BN + smB] = pb2.z; Bs[(kqB + 11) * BN + smB] = pb2.w;
        Bs[(kqB + 12) * BN + smB] = pb3.x; Bs[(kqB + 13) * BN + smB] = pb3.y;
        Bs[(kqB + 14) * BN + smB] = pb3.z; Bs[(kqB + 15) * BN + smB] = pb3.w;
        __syncthreads();

        // ---- issue global loads for tile g+1 (latency hidden behind compute of g)
        {
            int gn  = (g + 1) & (NTILES - 1);      // wraps to 0 on last iter (harmless)
            int n0n = (gn >> 4) * BN;
            int k0n = (gn & 15) * BK;
            const float* zp = zA + k0n;
            pa0 = *(const float4*)(zp + 0);
            pa1 = *(const float4*)(zp + 4);
            const float* ep = eB + (size_t)n0n * E_DIM + k0n;
            pb0 = *(const float4*)(ep + 0);
            pb1 = *(const float4*)(ep + 4);
            pb2 = *(const float4*)(ep + 8);
            pb3 = *(const float4*)(ep + 12);
        }

        // ---- compute tile g: sequential k order (bit-identical accumulation chain)
#pragma unroll 8
        for (int k = 0; k < BK; ++k) {
            float4 a0 = *(const float4*)&As[k * BM + ty * 16 + 0];   // wave-uniform
            float4 a1 = *(const float4*)&As[k * BM + ty * 16 + 4];   // broadcasts
            float4 a2 = *(const float4*)&As[k * BM + ty * 16 + 8];
            float4 a3 = *(const float4*)&As[k * BM + ty * 16 + 12];
            float4 b  = *(const float4*)&Bs[k * BN + tx * 4];        // conflict-free
            float av[16] = {a0.x, a0.y, a0.z, a0.w, a1.x, a1.y, a1.z, a1.w,
                            a2.x, a2.y, a2.z, a2.w, a3.x, a3.y, a3.z, a3.w};
            float bv[4]  = {b.x, b.y, b.z, b.w};
#pragma unroll
            for (int i = 0; i < 16; ++i)
#pragma unroll
                for (int j = 0; j < 4; ++j) acc[i][j] += av[i] * bv[j];
        }
        __syncthreads();

        // ---- end of an n0 block: fold into running argmin, reset acc
        if ((g & 15) == 15) {
            int n0 = (g >> 4) * BN;
#pragma unroll
            for (int j = 0; j < 4; ++j) {
                int n = n0 + tx * 4 + j;          // ascending within thread
#pragma unroll
                for (int i = 0; i < 16; ++i) {
                    float w = z2r[i] - 2.f * acc[i][j];
                    if (w < minw[i]) { minw[i] = w; mini[i] = n; }
                    acc[i][j] = 0.f;
                }
            }
        }
    }

    // ---- per-row argmin: all 64 candidates of a row live in this wave -> shuffle reduce
#pragma unroll
    for (int i = 0; i < 16; ++i) {
        float v = minw[i];
        int  ix = mini[i];
#pragma unroll
        for (int off = 1; off < 64; off <<= 1) {
            float vo = __shfl_xor(v, off);
            int   io = __shfl_xor(ix, off);
            if (vo < v || (vo == v && io < ix)) { v = vo; ix = io; }
        }
        if ((tid & 63) == 0) idxf_out[row0 + ty * 16 + i] = (float)ix;
    }
}

// ---------------- Kernel 3: gather + straight-through output + loss ----------------
__global__ __launch_bounds__(256) void output_kernel(const float* __restrict__ z,
                                                     const float* __restrict__ mask,
                                                     const float* __restrict__ emb,
                                                     const float* __restrict__ idxf,
                                                     float* __restrict__ out0,
                                                     float* __restrict__ loss) {
    const int nth = gridDim.x * blockDim.x;
    int t = blockIdx.x * blockDim.x + threadIdx.x;
    const float4* z4 = (const float4*)z;
    const float4* e4 = (const float4*)emb;
    float4* o4 = (float4*)out0;
    float partial = 0.f;
    for (int f = t; f < TOT_ELEMS / 4; f += nth) {
        int row = f >> 7;            // 128 float4 per 512-elem row
        int col = f & 127;
        int id  = (int)idxf[row];
        float m = mask[row];
        float4 zv = z4[f];
        float4 qv = e4[id * 128 + col];
        float dx = qv.x - zv.x, dy = qv.y - zv.y;
        float dz = qv.z - zv.z, dw = qv.w - zv.w;
        float4 ov;                   // z + (z_q - z): fp32 replication of ST estimator
        ov.x = zv.x + dx; ov.y = zv.y + dy;
        ov.z = zv.z + dz; ov.w = zv.w + dw;
        o4[f] = ov;
        partial += (dx * dx + dy * dy + dz * dz + dw * dw) * m;
    }
#pragma unroll
    for (int off = 32; off > 0; off >>= 1) partial += __shfl_down(partial, off);
    __shared__ float wsum[4];
    int lane = threadIdx.x & 63, w = threadIdx.x >> 6;
    if (lane == 0) wsum[w] = partial;
    __syncthreads();
    if (threadIdx.x == 0) {
        float s = wsum[0] + wsum[1] + wsum[2] + wsum[3];
        atomicAdd(loss, s * ((1.f + BETA) / (float)TOT_ELEMS));
    }
}

// ---------------- launcher (no d_ws usage) ----------------
extern "C" void kernel_launch(void* const* d_in, const int* in_sizes, int n_in,
                              void* d_out, int out_size, void* d_ws, size_t ws_size,
                              hipStream_t stream) {
    const float* z    = (const float*)d_in[0];   // (16,2048,512)
    const float* mask = (const float*)d_in[1];   // (16,2048)
    const float* emb  = (const float*)d_in[2];   // (8192,512)

    float* out0 = (float*)d_out;                 // z_q_st: 16777216 floats
    float* out1 = out0 + TOT_ELEMS;              // idx as float: 32768
    float* loss = out1 + NROWS;                  // scalar

    float* z2stash = out0;                       // out0[0:32768]; overwritten by output_kernel

    hipMemsetAsync(loss, 0, sizeof(float), stream);
    z2_kernel<<<NROWS / 4, 256, 0, stream>>>(z, z2stash);
    argmin_kernel<<<NROWS / BM, NTHREADS, 0, stream>>>(z, emb, z2stash, out1);
    output_kernel<<<4096, 256, 0, stream>>>(z, mask, emb, out1, out0, loss);
}